// Round 10
// baseline (164.555 us; speedup 1.0000x reference)
//
#include <hip/hip_runtime.h>

// B=8, C=128, H=W=64, G=8, K=9, Cg=16, Cd=64. NCHW, HW=4096.
// MFMA conventions (verified in-problem, round 2):
//   16x16: A lane&15=m, k-oct=(lane>>4)*8+j | C/D col=lane&15, row=(lane>>4)*4+r
//   32x32: A lane&31=m, k-oct=(lane>>5)*8+j | C/D col=lane&31, row=(r&3)+8*(r>>2)+4*(lane>>5)
//
// Round-13: occupancy + bank-conflict fixes on top of round-12's 32x32 phase 3.
//  * Rbuf stride 32 -> 36 floats (R9 doubled bank conflicts: 128B stride = same
//    bank quad for all lanes; 144B stride = step-4 banks, conflict-free).
//  * LDS envelope 65,536 -> 53,856 B => 3 blocks/CU (54,272 alloc, 3x = 162,816
//    <= 163,840; R4 measured occupancy 41% with this size vs 33-35% at 64KB).
//    omT f32[64][217] replaced by split oyL/oxL f32[64][73] + mskL f16[64][74]
//    (layout verified passing in R4). A3 relocated after Rbuf.
//  * __launch_bounds__(512,6) on k_omdcn.
//  k12 / k_prep / phase-3 math identical to round-12 (measured omdcn 49.2).

typedef __attribute__((ext_vector_type(8))) short short8;
typedef __attribute__((ext_vector_type(4))) float f32x4;
typedef __attribute__((ext_vector_type(16))) float f32x16;
typedef _Float16 __attribute__((ext_vector_type(2))) h2;

union F16u { f32x16 v; f32x4 q[4]; };

static __device__ __forceinline__ unsigned short f2bf(float x) {
    union { float f; unsigned int u; } v; v.f = x;
    return (unsigned short)((v.u + 0x7FFF + ((v.u >> 16) & 1)) >> 16);  // RNE
}
static __device__ __forceinline__ unsigned short f2h(float x) {
    union { _Float16 h; unsigned short u; } v; v.h = (_Float16)x;
    return v.u;
}

// ---------------- fused prep: blocks 0..127 = feat_s repack, 128..317 = weight packs
__global__ __launch_bounds__(256) void k_prep(const float* __restrict__ fs,
        uint4* __restrict__ fsT4, uint4* __restrict__ fsC4,
        const float* __restrict__ W_fsm, const float* __restrict__ W_off,
        const float* __restrict__ W_cat, const float* __restrict__ W_dcn,
        const float* __restrict__ W_om,
        unsigned short* __restrict__ wbfsm, unsigned short* __restrict__ wboff,
        unsigned short* __restrict__ wbcat, unsigned short* __restrict__ wbdcn,
        unsigned short* __restrict__ wb2) {
    __shared__ unsigned short st[64 * 136];
    const int t = threadIdx.x;
    if (blockIdx.x < 128) {
        unsigned int* st32 = (unsigned int*)st;
        const int b = blockIdx.x >> 4;
        const int p0 = (blockIdx.x & 15) << 6;
        for (int i = t; i < 64 * 64; i += 256) {
            int c2 = i >> 6, px = i & 63;
            float v0 = fs[(((b << 7) + 2 * c2) << 10) + p0 + px];
            float v1 = fs[(((b << 7) + 2 * c2 + 1) << 10) + p0 + px];
            st32[px * 68 + c2] = (unsigned int)f2bf(v0) | ((unsigned int)f2bf(v1) << 16);
        }
        __syncthreads();
        for (int i = t; i < 64 * 16; i += 256) {
            int px = i >> 4, q = i & 15;
            fsT4[(((b << 10) + p0 + px) << 4) + q] = ((const uint4*)(st + px * 136))[q];
        }
        __syncthreads();
        for (int i = t; i < 64 * 64; i += 256) {
            int c2 = i >> 6, px = i & 63;
            float v0 = fs[(((b << 7) + 2 * c2) << 10) + p0 + px];
            float v1 = fs[(((b << 7) + 2 * c2 + 1) << 10) + p0 + px];
            st32[px * 68 + c2] = (unsigned int)f2h(v0) | ((unsigned int)f2h(v1) << 16);
        }
        __syncthreads();
        // channel-major: fsC4[b][ci][p] , p = global fs pixel index (y2*32+x2)
        for (int i = t; i < 64 * 16; i += 256) {
            int ci = i >> 6, px = i & 63;
            fsC4[(b << 14) + (ci << 10) + p0 + px] = ((const uint4*)(st + px * 136))[ci];
        }
        return;
    }
    int idx = (blockIdx.x - 128) * 256 + t;
    int lane = idx & 63;
    int ml = lane & 15, kl = (lane >> 4) * 8;
    unsigned short tmp[8];
    if (idx < 2048) {                       // wbfsm: K=128, NT=8 (bf16)
        int r = idx >> 6;
        int o = (r % 8) * 16 + ml, k0 = (r / 8) * 32 + kl;
#pragma unroll
        for (int j = 0; j < 8; j++) tmp[j] = f2bf(W_fsm[o * 128 + k0 + j]);
        ((uint4*)wbfsm)[idx] = *(const uint4*)tmp;
    } else if (idx < 6144) {                // wboff: K=256, NT=8, x2 for k>=128 (bf16)
        int i2 = idx - 2048;
        int r = i2 >> 6;
        int o = (r % 8) * 16 + ml, k0 = (r / 8) * 32 + kl;
#pragma unroll
        for (int j = 0; j < 8; j++) {
            int k = k0 + j;
            float f = W_off[o * 256 + k];
            if (k >= 128) f *= 2.0f;
            tmp[j] = f2bf(f);
        }
        ((uint4*)wboff)[i2] = *(const uint4*)tmp;
    } else if (idx < 7168) {                // wbcat: K=64, NT=8 (bf16)
        int i2 = idx - 6144;
        int r = i2 >> 6;
        int o = (r % 8) * 16 + ml, k0 = (r / 8) * 32 + kl;
#pragma unroll
        for (int j = 0; j < 8; j++) tmp[j] = f2bf(W_cat[o * 64 + k0 + j]);
        ((uint4*)wbcat)[i2] = *(const uint4*)tmp;
    } else if (idx < 16384) {               // wbdcn: 32x32x16 B-frag [s][nt][lane] (f16)
        int i2 = idx - 7168;
        int r = i2 >> 6;                    // [0,144): r = s*2 + nt
        int o = (r & 1) * 32 + (lane & 31);
        int k0 = (r >> 1) * 16 + (lane >> 5) * 8;
#pragma unroll
        for (int j = 0; j < 8; j++) {
            int k = k0 + j;
            int g = k / 144;
            int rem = k - g * 144;
            tmp[j] = f2h(W_dcn[(o * 128 + g * 16 + (rem & 15)) * 9 + (rem >> 4)]);
        }
        ((uint4*)wbdcn)[i2] = *(const uint4*)tmp;
    } else if (idx < 48640) {               // wb2: K=(tap,c), NT=14 (N=224, pad o>=216) bf16
        int i2 = idx - 16384;
        int r = i2 >> 6;
        int nt = r % 14, kk = r / 14;
        int tap = kk >> 2, cc = kk & 3;
        int o = nt * 16 + ml;
        int c0 = cc * 32 + kl;
#pragma unroll
        for (int j = 0; j < 8; j++) {
            float v = (o < 216) ? W_om[(o * 128 + (c0 + j)) * 9 + tap] : 0.0f;
            tmp[j] = f2bf(v);
        }
        ((uint4*)wb2)[i2] = *(const uint4*)tmp;
    }
}

// ---------------- k12: fused fsm GEMM (K=128) + off GEMM (K=256)
// 512 blocks x 8 waves. wave = (ph = px-half, nq4 = N-quarter).
__global__ __launch_bounds__(512, 6) void k12(const float* __restrict__ feat_l,
        const uint4* __restrict__ fsT4,
        const unsigned short* __restrict__ wbf, const unsigned short* __restrict__ wbo,
        const float* __restrict__ s_fsm, const float* __restrict__ b_fsm,
        const float* __restrict__ s_off, const float* __restrict__ b_off,
        float* __restrict__ feat_arm, unsigned short* __restrict__ offT) {
    __shared__ unsigned short A1[64 * 136];
    __shared__ unsigned short A2[64 * 264];
    const int t = threadIdx.x;
    const int b = blockIdx.x >> 6;
    const int h = blockIdx.x & 63;
    const int hw0 = h << 6;
    unsigned int* A1w = (unsigned int*)A1;
    for (int i = t; i < 64 * 64; i += 512) {
        int c2 = i >> 6, px = i & 63;
        float v0 = feat_l[(((b << 7) + 2 * c2) << 12) + hw0 + px];
        float v1 = feat_l[(((b << 7) + 2 * c2 + 1) << 12) + hw0 + px];
        A1w[px * 68 + c2] = (unsigned int)f2bf(v0) | ((unsigned int)f2bf(v1) << 16);
    }
    {
        const int h2 = h >> 1;
        int px2 = t >> 4, q = t & 15;
        uint4 v = fsT4[(((b << 10) + (h2 << 5) + px2) << 4) + q];
        ((uint4*)(A2 + (2 * px2) * 264 + 128))[q] = v;
        ((uint4*)(A2 + (2 * px2 + 1) * 264 + 128))[q] = v;
    }
    __syncthreads();
    const int lane = t & 63;
    const int w = __builtin_amdgcn_readfirstlane(t >> 6);
    const int ph = w & 1;    // px half
    const int nq4 = w >> 1;  // N quarter
    const int m = lane & 15, ko = lane >> 4;
    f32x4 acc[2][2];   // [mt][nt2]
#pragma unroll
    for (int i = 0; i < 2; i++)
#pragma unroll
        for (int j = 0; j < 2; j++) acc[i][j] = (f32x4){0.f, 0.f, 0.f, 0.f};
#pragma unroll
    for (int kk = 0; kk < 4; kk++) {
        short8 a8[2];
#pragma unroll
        for (int mt = 0; mt < 2; mt++)
            a8[mt] = *(const short8*)(A1 + ((ph << 5) + (mt << 4) + m) * 136 + kk * 32 + ko * 8);
#pragma unroll
        for (int nt2 = 0; nt2 < 2; nt2++) {
            uint4 bu = ((const uint4*)wbf)[((kk << 3) + (nq4 << 1) + nt2) * 64 + lane];
#pragma unroll
            for (int mt = 0; mt < 2; mt++)
                acc[mt][nt2] = __builtin_amdgcn_mfma_f32_16x16x32_bf16(
                    a8[mt], *(short8*)&bu, acc[mt][nt2], 0, 0, 0);
        }
    }
    // fsm epilogue: bf16 -> A2 (off GEMM input) + direct float4 feat_arm store
#pragma unroll
    for (int nt2 = 0; nt2 < 2; nt2++) {
        int o = (((nq4 << 1) + nt2) << 4) + m;
        float sc = s_fsm[o], bi = b_fsm[o];
#pragma unroll
        for (int mt = 0; mt < 2; mt++) {
            int px0 = (ph << 5) + (mt << 4) + (ko << 2);
            f32x4 v;
#pragma unroll
            for (int r = 0; r < 4; r++) {
                float vv = fmaf(acc[mt][nt2][r], sc, bi);
                vv = vv > 0.f ? vv : 0.f;
                v[r] = vv;
                A2[(px0 + r) * 264 + o] = f2bf(vv);
            }
            *(f32x4*)(feat_arm + ((((b << 7) + o) << 12) + hw0 + px0)) = v;
        }
    }
    __syncthreads();
    f32x4 acc2[2][2];
#pragma unroll
    for (int i = 0; i < 2; i++)
#pragma unroll
        for (int j = 0; j < 2; j++) acc2[i][j] = (f32x4){0.f, 0.f, 0.f, 0.f};
#pragma unroll
    for (int kk = 0; kk < 8; kk++) {
        short8 a8[2];
#pragma unroll
        for (int mt = 0; mt < 2; mt++)
            a8[mt] = *(const short8*)(A2 + ((ph << 5) + (mt << 4) + m) * 264 + kk * 32 + ko * 8);
#pragma unroll
        for (int nt2 = 0; nt2 < 2; nt2++) {
            uint4 bu = ((const uint4*)wbo)[((kk << 3) + (nq4 << 1) + nt2) * 64 + lane];
#pragma unroll
            for (int mt = 0; mt < 2; mt++)
                acc2[mt][nt2] = __builtin_amdgcn_mfma_f32_16x16x32_bf16(
                    a8[mt], *(short8*)&bu, acc2[mt][nt2], 0, 0, 0);
        }
    }
    __syncthreads();
#pragma unroll
    for (int nt2 = 0; nt2 < 2; nt2++) {
        int o = (((nq4 << 1) + nt2) << 4) + m;
        float sc = s_off[o], bi = b_off[o];
#pragma unroll
        for (int mt = 0; mt < 2; mt++) {
            int px0 = (ph << 5) + (mt << 4) + (ko << 2);
#pragma unroll
            for (int r = 0; r < 4; r++) {
                float v = fmaf(acc2[mt][nt2][r], sc, bi);
                v = v > 0.f ? v : 0.f;
                A2[(px0 + r) * 264 + o] = f2bf(v);
            }
        }
    }
    __syncthreads();
    for (int i = t; i < 64 * 16; i += 512) {
        int px = i >> 4, q = i & 15;
        ((uint4*)offT)[(((b << 12) + hw0 + px) << 4) + q] = ((const uint4*)(A2 + px * 264))[q];
    }
}

// ---------------- k_omdcn: FUSED conv3x3(om) -> LDS -> DCNv2 sample -> cat GEMM -> feat
// 512 blocks (b, row h) x 8 waves (512 threads). LDS 53,856 B -> 3 blocks/CU.
// Overlays (barrier-separated):
//   st [198][136] shorts                  0 .. 53,856 B   (conv input stage)
//   oyL f32[64][73] 0..18,688 | oxL 18,688..37,376 | mskL f16[64][74] 37,376..46,848
//   Rbuf 4 x 64 x 36 f (stride 36 = conflict-free)  0..36,864 | A3 36,864..46,080
__global__ __launch_bounds__(512, 6) void k_omdcn(
        const unsigned short* __restrict__ offT, const uint4* __restrict__ fsC4,
        const unsigned short* __restrict__ Wb2, const float* __restrict__ bom,
        const unsigned short* __restrict__ wbd, const float* __restrict__ bd,
        const unsigned short* __restrict__ wbc,
        const float* __restrict__ s_cat, const float* __restrict__ b_cat,
        const float* __restrict__ feat_arm, float* __restrict__ feat) {
    __shared__ float LDSf[13464];                          // 53,856 B
    unsigned short* st = (unsigned short*)LDSf;
    float* oyL = LDSf;                                     // [64][73]
    float* oxL = LDSf + 4672;                              // [64][73]
    unsigned short* mskL = (unsigned short*)(LDSf + 9344); // [64][74] f16
    float* Rbuf = LDSf;                                    // 4 x 64 x 36 f
    unsigned short* A3 = (unsigned short*)(LDSf + 9216);   // [64][72] bf16 @36,864
    const uint4* offT4 = (const uint4*)offT;
    const uint4* W4 = (const uint4*)Wb2;
    const uint4* wbd4 = (const uint4*)wbd;
    const int t = threadIdx.x;
    const int b = blockIdx.x >> 6;
    const int h = blockIdx.x & 63;
    // ---- stage conv input rows h-1..h+1, 66 px, zero pad
    for (int i = t; i < 3 * 66 * 16; i += 512) {
        int q = i & 15;
        int rp = i >> 4;
        int r = rp / 66, p = rp - r * 66;
        int gy = h + r - 1, gx = p - 1;
        uint4 v = make_uint4(0, 0, 0, 0);
        if (gy >= 0 && gy < 64 && gx >= 0 && gx < 64)
            v = offT4[((((b << 6) + gy) << 6) + gx) * 16 + q];
        ((uint4*)(st + rp * 136))[q] = v;
    }
    __syncthreads();
    const int lane = t & 63;
    const int w = __builtin_amdgcn_readfirstlane(t >> 6);
    const int m = lane & 15, ko = lane >> 4;
    // ---- phase 1: conv3x3, N-split over 14 tiles: waves 0..6 own {2w,2w+1}
    f32x4 acc[2][4];   // [nt2][mt]
#pragma unroll
    for (int i = 0; i < 2; i++)
#pragma unroll
        for (int j = 0; j < 4; j++) acc[i][j] = (f32x4){0.f, 0.f, 0.f, 0.f};
    if (w < 7) {
        const int ntb = w << 1;
        uint4 b4c[2];
#pragma unroll
        for (int nt2 = 0; nt2 < 2; nt2++)
            b4c[nt2] = W4[((ntb + nt2) << 6) + lane];
#pragma unroll
        for (int kk = 0; kk < 36; kk++) {
            const int tap = kk >> 2, cc = kk & 3;
            const int dy = tap / 3, dx = tap - dy * 3;
            uint4 b4n[2];
            if (kk < 35) {
#pragma unroll
                for (int nt2 = 0; nt2 < 2; nt2++)
                    b4n[nt2] = W4[(((kk + 1) * 14 + ntb + nt2) << 6) + lane];
            }
            short8 a8[4];
#pragma unroll
            for (int mt = 0; mt < 4; mt++) {
                int p = mt * 16 + m + dx;
                a8[mt] = *(const short8*)(st + (dy * 66 + p) * 136 + (cc << 5) + (ko << 3));
            }
            __builtin_amdgcn_s_setprio(1);
#pragma unroll
            for (int nt2 = 0; nt2 < 2; nt2++)
#pragma unroll
                for (int mt = 0; mt < 4; mt++)
                    acc[nt2][mt] = __builtin_amdgcn_mfma_f32_16x16x32_bf16(
                        a8[mt], *(short8*)&b4c[nt2], acc[nt2][mt], 0, 0, 0);
            __builtin_amdgcn_s_setprio(0);
            if (kk < 35) {
#pragma unroll
                for (int nt2 = 0; nt2 < 2; nt2++) b4c[nt2] = b4n[nt2];
            }
        }
    }
    __syncthreads();                       // stage reads done -> om overlay safe
    // ---- phase 2: om -> split LDS; sigmoid applied to mask channels (f16)
    if (w < 7) {
#pragma unroll
        for (int nt2 = 0; nt2 < 2; nt2++) {
            int o = (((w << 1) + nt2) << 4) + m;
            if (o < 216) {
                float bv = bom[o];
#pragma unroll
                for (int mt = 0; mt < 4; mt++) {
                    f32x4 v = acc[nt2][mt];
#pragma unroll
                    for (int r = 0; r < 4; r++) {
                        int px = mt * 16 + (ko << 2) + r;
                        float val = v[r] + bv;
                        if (o < 72) {
                            oyL[px * 73 + o] = val;
                        } else if (o < 144) {
                            oxL[px * 73 + (o - 72)] = val;
                        } else {
                            float sg = 1.0f / (1.0f + __expf(-val));
                            mskL[px * 74 + (o - 144)] = f2h(sg);
                        }
                    }
                }
            }
        }
    }
    __syncthreads();
    // ---- phase 3: DCN sampling, 32x32x16 f16; wave = (px-half p2, K-quarter kq)
    // step s = kq*18+si: tap = si%9 (compile-time), g = 2kq+(si>=9), ch = s.
    const int p2 = w & 1;
    const int kq = w >> 1;
    const int oct = lane >> 5;
    const int l31 = lane & 31;
    const int px = (p2 << 5) + l31;
    const float fh = (float)h, fw = (float)px;
    const int b14 = b << 14;
    const float* oyrow = oyL + px * 73 + kq * 18;
    const float* oxrow = oxL + px * 73 + kq * 18;
    const unsigned short* mrow = mskL + px * 74 + kq * 18;
    const uint4* bp0 = fsC4 + b14 + (((kq << 2) + oct) << 10);
    const uint4* wbbase = wbd4 + (kq * 36) * 64 + lane;
    F16u acc3[2];
#pragma unroll
    for (int nt = 0; nt < 2; nt++)
#pragma unroll
        for (int q = 0; q < 4; q++) acc3[nt].q[q] = (f32x4){0.f, 0.f, 0.f, 0.f};
#pragma unroll
    for (int si = 0; si < 18; si++) {
        const int tap = si % 9;
        const int dy = tap / 3, dx = tap - dy * 3;
        float oy = oyrow[si];
        float ox = oxrow[si];
        float mmv = (float)(*(const _Float16*)(mrow + si));  // pre-sigmoided
        float py = fh + (float)(dy - 1) + oy;
        float pxx = fw + (float)(dx - 1) + ox;
        float y0f = floorf(py), x0f = floorf(pxx);
        float tyf = py - y0f, txf = pxx - x0f;
        int y0i = (int)y0f, x0i = (int)x0f;
        int y1i = y0i + 1, x1i = x0i + 1;
        bool vy0 = (y0i >= 0) && (y0i < 64);
        bool vy1 = (y1i >= 0) && (y1i < 64);
        bool vx0 = (x0i >= 0) && (x0i < 64);
        bool vx1 = (x1i >= 0) && (x1i < 64);
        float w00 = (vy0 && vx0) ? (1.0f - tyf) * (1.0f - txf) * mmv : 0.0f;
        float w01 = (vy0 && vx1) ? (1.0f - tyf) * txf * mmv : 0.0f;
        float w10 = (vy1 && vx0) ? tyf * (1.0f - txf) * mmv : 0.0f;
        float w11 = (vy1 && vx1) ? tyf * txf * mmv : 0.0f;
        int yc0 = y0i < 0 ? 0 : (y0i > 63 ? 63 : y0i);
        int yc1 = y1i < 0 ? 0 : (y1i > 63 ? 63 : y1i);
        int xc0 = x0i < 0 ? 0 : (x0i > 63 ? 63 : x0i);
        int xc1 = x1i < 0 ? 0 : (x1i > 63 ? 63 : x1i);
        int row0 = (yc0 >> 1) << 5, row1 = (yc1 >> 1) << 5;
        const uint4* bpp = (si < 9) ? bp0 : (bp0 + 2048);  // g += 1 -> ci += 2 planes
        uint4 c00 = bpp[row0 + (xc0 >> 1)];
        uint4 c01 = bpp[row0 + (xc1 >> 1)];
        uint4 c10 = bpp[row1 + (xc0 >> 1)];
        uint4 c11 = bpp[row1 + (xc1 >> 1)];
        _Float16 h00 = (_Float16)w00, h01 = (_Float16)w01;
        _Float16 h10 = (_Float16)w10, h11 = (_Float16)w11;
        h2 W00 = (h2){h00, h00}, W01 = (h2){h01, h01};
        h2 W10 = (h2){h10, h10}, W11 = (h2){h11, h11};
        union { uint4 u; h2 h[4]; } U00, U01, U10, U11;
        U00.u = c00; U01.u = c01; U10.u = c10; U11.u = c11;
        union { short8 s; h2 h[4]; } av;
#pragma unroll
        for (int c = 0; c < 4; c++)
            av.h[c] = U00.h[c] * W00 + U01.h[c] * W01 + U10.h[c] * W10 + U11.h[c] * W11;
        uint4 bu0 = wbbase[(si * 2) * 64];
        uint4 bu1 = wbbase[(si * 2 + 1) * 64];
        __builtin_amdgcn_s_setprio(1);
        acc3[0].v = __builtin_amdgcn_mfma_f32_32x32x16_f16(av.s, *(short8*)&bu0, acc3[0].v, 0, 0, 0);
        acc3[1].v = __builtin_amdgcn_mfma_f32_32x32x16_f16(av.s, *(short8*)&bu1, acc3[1].v, 0, 0, 0);
        __builtin_amdgcn_s_setprio(0);
    }
    __syncthreads();                       // om reads done -> Rbuf overlay safe
    // ---- 4-quarter reduction, two rounds through Rbuf (stride 36 f, conflict-free)
    if (kq >= 2) {
        float* rb = Rbuf + ((((kq - 2) << 1) + p2) * 64 + lane) * 36;
#pragma unroll
        for (int nt = 0; nt < 2; nt++)
#pragma unroll
            for (int q = 0; q < 4; q++)
                *(f32x4*)(rb + (nt << 4) + (q << 2)) = acc3[nt].q[q];
    }
    __syncthreads();
    if (kq < 2) {
        const float* rb = Rbuf + (((kq << 1) + p2) * 64 + lane) * 36;
#pragma unroll
        for (int nt = 0; nt < 2; nt++)
#pragma unroll
            for (int q = 0; q < 4; q++)
                acc3[nt].q[q] += *(const f32x4*)(rb + (nt << 4) + (q << 2));
    }
    __syncthreads();
    if (kq == 1) {
        float* rb = Rbuf + (p2 * 64 + lane) * 36;
#pragma unroll
        for (int nt = 0; nt < 2; nt++)
#pragma unroll
            for (int q = 0; q < 4; q++)
                *(f32x4*)(rb + (nt << 4) + (q << 2)) = acc3[nt].q[q];
    }
    __syncthreads();
    if (kq == 0) {
        const float* rb = Rbuf + (p2 * 64 + lane) * 36;
#pragma unroll
        for (int nt = 0; nt < 2; nt++)
#pragma unroll
            for (int q = 0; q < 4; q++)
                acc3[nt].q[q] += *(const f32x4*)(rb + (nt << 4) + (q << 2));
        // ---- phase 4a: align -> A3 bf16 [px][72]; 32x32 C/D mapping
#pragma unroll
        for (int nt = 0; nt < 2; nt++) {
            int o = (nt << 5) + l31;
            float bv = bd[o];
#pragma unroll
            for (int r = 0; r < 16; r++) {
                int rowm = (r & 3) + ((r >> 2) << 3) + (oct << 2);
                float v = acc3[nt].v[r] + bv;
                v = v > 0.f ? v : 0.f;
                A3[((p2 << 5) + rowm) * 72 + o] = f2bf(v);
            }
        }
    }
    __syncthreads();                       // A3 visible to all waves
    // ---- phase 4b: cat GEMM K=64, N=128 (16x16); wave = (px quarter nq, N-half kh)
    const int nq = w & 3;
    const int kh = w >> 2;
    f32x4 acc2[4];
#pragma unroll
    for (int nt2 = 0; nt2 < 4; nt2++) acc2[nt2] = (f32x4){0.f, 0.f, 0.f, 0.f};
#pragma unroll
    for (int kk2 = 0; kk2 < 2; kk2++) {
        short8 av = *(const short8*)(A3 + ((nq << 4) + m) * 72 + kk2 * 32 + (ko << 3));
#pragma unroll
        for (int nt2 = 0; nt2 < 4; nt2++) {
            uint4 bu = ((const uint4*)wbc)[(kk2 * 8 + (kh << 2) + nt2) * 64 + lane];
            acc2[nt2] = __builtin_amdgcn_mfma_f32_16x16x32_bf16(av, *(short8*)&bu, acc2[nt2], 0, 0, 0);
        }
    }
    // ---- phase 4c: direct float4 epilogue (feat_arm preload + fused store)
    {
        const int px0 = (nq << 4) + (ko << 2);
        const int base = (b << 19) + (h << 6) + px0;
        f32x4 fa[4];
#pragma unroll
        for (int nt2 = 0; nt2 < 4; nt2++) {
            int o = (((kh << 2) + nt2) << 4) + m;
            fa[nt2] = *(const f32x4*)(feat_arm + base + (o << 12));
        }
#pragma unroll
        for (int nt2 = 0; nt2 < 4; nt2++) {
            int o = (((kh << 2) + nt2) << 4) + m;
            float sc = s_cat[o], bi = b_cat[o];
            f32x4 v;
#pragma unroll
            for (int r = 0; r < 4; r++) {
                float vv = fmaf(acc2[nt2][r], sc, bi);
                vv = vv > 0.f ? vv : 0.f;
                v[r] = vv + fa[nt2][r];
            }
            *(f32x4*)(feat + base + (o << 12)) = v;
        }
    }
}

extern "C" void kernel_launch(void* const* d_in, const int* in_sizes, int n_in,
                              void* d_out, int out_size, void* d_ws, size_t ws_size,
                              hipStream_t stream) {
    const float* feat_l = (const float*)d_in[0];
    const float* feat_s = (const float*)d_in[1];
    const float* W_fsm  = (const float*)d_in[2];
    const float* s_fsm  = (const float*)d_in[3];
    const float* b_fsm  = (const float*)d_in[4];
    const float* W_off  = (const float*)d_in[5];
    const float* s_off  = (const float*)d_in[6];
    const float* b_off  = (const float*)d_in[7];
    const float* W_om   = (const float*)d_in[8];
    const float* b_om   = (const float*)d_in[9];
    const float* W_dcn  = (const float*)d_in[10];
    const float* b_dcn  = (const float*)d_in[11];
    const float* W_cat  = (const float*)d_in[12];
    const float* s_cat  = (const float*)d_in[13];
    const float* b_cat  = (const float*)d_in[14];

    float* feat     = (float*)d_out;
    float* feat_arm = feat + 4194304;

    float* ws = (float*)d_ws;
    unsigned short* offT = (unsigned short*)ws;                // 2,097,152 f
    uint4* fsT4  = (uint4*)(ws + 9175040);                     //   524,288 f
    unsigned short* wb2   = (unsigned short*)(ws + 9699328);   //  147,456 f
    unsigned short* wbfsm = (unsigned short*)(ws + 9846784);   //    8,192 f
    unsigned short* wboff = (unsigned short*)(ws + 9854976);   //   16,384 f
    unsigned short* wbcat = (unsigned short*)(ws + 9871360);   //    4,096 f
    unsigned short* wbdcn = (unsigned short*)(ws + 9875456);   //   36,864 f
    uint4* fsC4  = (uint4*)(ws + 9912320);                     //   524,288 f

    k_prep<<<318, 256, 0, stream>>>(feat_s, fsT4, fsC4, W_fsm, W_off, W_cat,
                                    W_dcn, W_om, wbfsm, wboff, wbcat, wbdcn, wb2);

    k12<<<512, 512, 0, stream>>>(feat_l, fsT4, wbfsm, wboff,
                                 s_fsm, b_fsm, s_off, b_off, feat_arm, offT);
    k_omdcn<<<512, 512, 0, stream>>>(offT, fsC4, wb2, b_om, wbdcn, b_dcn,
                                     wbcat, s_cat, b_cat, feat_arm, feat);
}

// Round 12
// 155.153 us; speedup vs baseline: 1.0606x; 1.0606x over previous
//
#include <hip/hip_runtime.h>

// B=8, C=128, H=W=64, G=8, K=9, Cg=16, Cd=64. NCHW, HW=4096.
// MFMA conventions (verified in-problem, round 2):
//   16x16: A lane&15=m, k-oct=(lane>>4)*8+j | C/D col=lane&15, row=(lane>>4)*4+r
//   32x32: A lane&31=m, k-oct=(lane>>5)*8+j | C/D col=lane&31, row=(r&3)+8*(r>>2)+4*(lane>>5)
//
// Round-15: RESUBMIT of round-14 (container infra failure, no measurement).
//  R10 regression isolated: __launch_bounds__(512,6) forced VGPR 52->40 ->
//  scratch spills (+13MB WRITE, +6MB FETCH per dispatch, +5us). Grid is 512
//  blocks = 2/CU, so the smaller LDS never could add a resident block anyway.
//  * k_omdcn back to __launch_bounds__(512,4)  (no spill).
//  * KEEP: Rbuf stride 36 (bank conflicts 4.4M -> 2.26M, verified R10).
//  * KEEP: 32x32x16 phase 3, split oy/ox/msk LDS layout, small 53,856B envelope.
//  k12 / k_prep identical to round-13.

typedef __attribute__((ext_vector_type(8))) short short8;
typedef __attribute__((ext_vector_type(4))) float f32x4;
typedef __attribute__((ext_vector_type(16))) float f32x16;
typedef _Float16 __attribute__((ext_vector_type(2))) h2;

union F16u { f32x16 v; f32x4 q[4]; };

static __device__ __forceinline__ unsigned short f2bf(float x) {
    union { float f; unsigned int u; } v; v.f = x;
    return (unsigned short)((v.u + 0x7FFF + ((v.u >> 16) & 1)) >> 16);  // RNE
}
static __device__ __forceinline__ unsigned short f2h(float x) {
    union { _Float16 h; unsigned short u; } v; v.h = (_Float16)x;
    return v.u;
}

// ---------------- fused prep: blocks 0..127 = feat_s repack, 128..317 = weight packs
__global__ __launch_bounds__(256) void k_prep(const float* __restrict__ fs,
        uint4* __restrict__ fsT4, uint4* __restrict__ fsC4,
        const float* __restrict__ W_fsm, const float* __restrict__ W_off,
        const float* __restrict__ W_cat, const float* __restrict__ W_dcn,
        const float* __restrict__ W_om,
        unsigned short* __restrict__ wbfsm, unsigned short* __restrict__ wboff,
        unsigned short* __restrict__ wbcat, unsigned short* __restrict__ wbdcn,
        unsigned short* __restrict__ wb2) {
    __shared__ unsigned short st[64 * 136];
    const int t = threadIdx.x;
    if (blockIdx.x < 128) {
        unsigned int* st32 = (unsigned int*)st;
        const int b = blockIdx.x >> 4;
        const int p0 = (blockIdx.x & 15) << 6;
        for (int i = t; i < 64 * 64; i += 256) {
            int c2 = i >> 6, px = i & 63;
            float v0 = fs[(((b << 7) + 2 * c2) << 10) + p0 + px];
            float v1 = fs[(((b << 7) + 2 * c2 + 1) << 10) + p0 + px];
            st32[px * 68 + c2] = (unsigned int)f2bf(v0) | ((unsigned int)f2bf(v1) << 16);
        }
        __syncthreads();
        for (int i = t; i < 64 * 16; i += 256) {
            int px = i >> 4, q = i & 15;
            fsT4[(((b << 10) + p0 + px) << 4) + q] = ((const uint4*)(st + px * 136))[q];
        }
        __syncthreads();
        for (int i = t; i < 64 * 64; i += 256) {
            int c2 = i >> 6, px = i & 63;
            float v0 = fs[(((b << 7) + 2 * c2) << 10) + p0 + px];
            float v1 = fs[(((b << 7) + 2 * c2 + 1) << 10) + p0 + px];
            st32[px * 68 + c2] = (unsigned int)f2h(v0) | ((unsigned int)f2h(v1) << 16);
        }
        __syncthreads();
        // channel-major: fsC4[b][ci][p] , p = global fs pixel index (y2*32+x2)
        for (int i = t; i < 64 * 16; i += 256) {
            int ci = i >> 6, px = i & 63;
            fsC4[(b << 14) + (ci << 10) + p0 + px] = ((const uint4*)(st + px * 136))[ci];
        }
        return;
    }
    int idx = (blockIdx.x - 128) * 256 + t;
    int lane = idx & 63;
    int ml = lane & 15, kl = (lane >> 4) * 8;
    unsigned short tmp[8];
    if (idx < 2048) {                       // wbfsm: K=128, NT=8 (bf16)
        int r = idx >> 6;
        int o = (r % 8) * 16 + ml, k0 = (r / 8) * 32 + kl;
#pragma unroll
        for (int j = 0; j < 8; j++) tmp[j] = f2bf(W_fsm[o * 128 + k0 + j]);
        ((uint4*)wbfsm)[idx] = *(const uint4*)tmp;
    } else if (idx < 6144) {                // wboff: K=256, NT=8, x2 for k>=128 (bf16)
        int i2 = idx - 2048;
        int r = i2 >> 6;
        int o = (r % 8) * 16 + ml, k0 = (r / 8) * 32 + kl;
#pragma unroll
        for (int j = 0; j < 8; j++) {
            int k = k0 + j;
            float f = W_off[o * 256 + k];
            if (k >= 128) f *= 2.0f;
            tmp[j] = f2bf(f);
        }
        ((uint4*)wboff)[i2] = *(const uint4*)tmp;
    } else if (idx < 7168) {                // wbcat: K=64, NT=8 (bf16)
        int i2 = idx - 6144;
        int r = i2 >> 6;
        int o = (r % 8) * 16 + ml, k0 = (r / 8) * 32 + kl;
#pragma unroll
        for (int j = 0; j < 8; j++) tmp[j] = f2bf(W_cat[o * 64 + k0 + j]);
        ((uint4*)wbcat)[i2] = *(const uint4*)tmp;
    } else if (idx < 16384) {               // wbdcn: 32x32x16 B-frag [s][nt][lane] (f16)
        int i2 = idx - 7168;
        int r = i2 >> 6;                    // [0,144): r = s*2 + nt
        int o = (r & 1) * 32 + (lane & 31);
        int k0 = (r >> 1) * 16 + (lane >> 5) * 8;
#pragma unroll
        for (int j = 0; j < 8; j++) {
            int k = k0 + j;
            int g = k / 144;
            int rem = k - g * 144;
            tmp[j] = f2h(W_dcn[(o * 128 + g * 16 + (rem & 15)) * 9 + (rem >> 4)]);
        }
        ((uint4*)wbdcn)[i2] = *(const uint4*)tmp;
    } else if (idx < 48640) {               // wb2: K=(tap,c), NT=14 (N=224, pad o>=216) bf16
        int i2 = idx - 16384;
        int r = i2 >> 6;
        int nt = r % 14, kk = r / 14;
        int tap = kk >> 2, cc = kk & 3;
        int o = nt * 16 + ml;
        int c0 = cc * 32 + kl;
#pragma unroll
        for (int j = 0; j < 8; j++) {
            float v = (o < 216) ? W_om[(o * 128 + (c0 + j)) * 9 + tap] : 0.0f;
            tmp[j] = f2bf(v);
        }
        ((uint4*)wb2)[i2] = *(const uint4*)tmp;
    }
}

// ---------------- k12: fused fsm GEMM (K=128) + off GEMM (K=256)
// 512 blocks x 8 waves. wave = (ph = px-half, nq4 = N-quarter).
__global__ __launch_bounds__(512, 6) void k12(const float* __restrict__ feat_l,
        const uint4* __restrict__ fsT4,
        const unsigned short* __restrict__ wbf, const unsigned short* __restrict__ wbo,
        const float* __restrict__ s_fsm, const float* __restrict__ b_fsm,
        const float* __restrict__ s_off, const float* __restrict__ b_off,
        float* __restrict__ feat_arm, unsigned short* __restrict__ offT) {
    __shared__ unsigned short A1[64 * 136];
    __shared__ unsigned short A2[64 * 264];
    const int t = threadIdx.x;
    const int b = blockIdx.x >> 6;
    const int h = blockIdx.x & 63;
    const int hw0 = h << 6;
    unsigned int* A1w = (unsigned int*)A1;
    for (int i = t; i < 64 * 64; i += 512) {
        int c2 = i >> 6, px = i & 63;
        float v0 = feat_l[(((b << 7) + 2 * c2) << 12) + hw0 + px];
        float v1 = feat_l[(((b << 7) + 2 * c2 + 1) << 12) + hw0 + px];
        A1w[px * 68 + c2] = (unsigned int)f2bf(v0) | ((unsigned int)f2bf(v1) << 16);
    }
    {
        const int h2 = h >> 1;
        int px2 = t >> 4, q = t & 15;
        uint4 v = fsT4[(((b << 10) + (h2 << 5) + px2) << 4) + q];
        ((uint4*)(A2 + (2 * px2) * 264 + 128))[q] = v;
        ((uint4*)(A2 + (2 * px2 + 1) * 264 + 128))[q] = v;
    }
    __syncthreads();
    const int lane = t & 63;
    const int w = __builtin_amdgcn_readfirstlane(t >> 6);
    const int ph = w & 1;    // px half
    const int nq4 = w >> 1;  // N quarter
    const int m = lane & 15, ko = lane >> 4;
    f32x4 acc[2][2];   // [mt][nt2]
#pragma unroll
    for (int i = 0; i < 2; i++)
#pragma unroll
        for (int j = 0; j < 2; j++) acc[i][j] = (f32x4){0.f, 0.f, 0.f, 0.f};
#pragma unroll
    for (int kk = 0; kk < 4; kk++) {
        short8 a8[2];
#pragma unroll
        for (int mt = 0; mt < 2; mt++)
            a8[mt] = *(const short8*)(A1 + ((ph << 5) + (mt << 4) + m) * 136 + kk * 32 + ko * 8);
#pragma unroll
        for (int nt2 = 0; nt2 < 2; nt2++) {
            uint4 bu = ((const uint4*)wbf)[((kk << 3) + (nq4 << 1) + nt2) * 64 + lane];
#pragma unroll
            for (int mt = 0; mt < 2; mt++)
                acc[mt][nt2] = __builtin_amdgcn_mfma_f32_16x16x32_bf16(
                    a8[mt], *(short8*)&bu, acc[mt][nt2], 0, 0, 0);
        }
    }
    // fsm epilogue: bf16 -> A2 (off GEMM input) + direct float4 feat_arm store
#pragma unroll
    for (int nt2 = 0; nt2 < 2; nt2++) {
        int o = (((nq4 << 1) + nt2) << 4) + m;
        float sc = s_fsm[o], bi = b_fsm[o];
#pragma unroll
        for (int mt = 0; mt < 2; mt++) {
            int px0 = (ph << 5) + (mt << 4) + (ko << 2);
            f32x4 v;
#pragma unroll
            for (int r = 0; r < 4; r++) {
                float vv = fmaf(acc[mt][nt2][r], sc, bi);
                vv = vv > 0.f ? vv : 0.f;
                v[r] = vv;
                A2[(px0 + r) * 264 + o] = f2bf(vv);
            }
            *(f32x4*)(feat_arm + ((((b << 7) + o) << 12) + hw0 + px0)) = v;
        }
    }
    __syncthreads();
    f32x4 acc2[2][2];
#pragma unroll
    for (int i = 0; i < 2; i++)
#pragma unroll
        for (int j = 0; j < 2; j++) acc2[i][j] = (f32x4){0.f, 0.f, 0.f, 0.f};
#pragma unroll
    for (int kk = 0; kk < 8; kk++) {
        short8 a8[2];
#pragma unroll
        for (int mt = 0; mt < 2; mt++)
            a8[mt] = *(const short8*)(A2 + ((ph << 5) + (mt << 4) + m) * 264 + kk * 32 + ko * 8);
#pragma unroll
        for (int nt2 = 0; nt2 < 2; nt2++) {
            uint4 bu = ((const uint4*)wbo)[((kk << 3) + (nq4 << 1) + nt2) * 64 + lane];
#pragma unroll
            for (int mt = 0; mt < 2; mt++)
                acc2[mt][nt2] = __builtin_amdgcn_mfma_f32_16x16x32_bf16(
                    a8[mt], *(short8*)&bu, acc2[mt][nt2], 0, 0, 0);
        }
    }
    __syncthreads();
#pragma unroll
    for (int nt2 = 0; nt2 < 2; nt2++) {
        int o = (((nq4 << 1) + nt2) << 4) + m;
        float sc = s_off[o], bi = b_off[o];
#pragma unroll
        for (int mt = 0; mt < 2; mt++) {
            int px0 = (ph << 5) + (mt << 4) + (ko << 2);
#pragma unroll
            for (int r = 0; r < 4; r++) {
                float v = fmaf(acc2[mt][nt2][r], sc, bi);
                v = v > 0.f ? v : 0.f;
                A2[(px0 + r) * 264 + o] = f2bf(v);
            }
        }
    }
    __syncthreads();
    for (int i = t; i < 64 * 16; i += 512) {
        int px = i >> 4, q = i & 15;
        ((uint4*)offT)[(((b << 12) + hw0 + px) << 4) + q] = ((const uint4*)(A2 + px * 264))[q];
    }
}

// ---------------- k_omdcn: FUSED conv3x3(om) -> LDS -> DCNv2 sample -> cat GEMM -> feat
// 512 blocks (b, row h) x 8 waves (512 threads). LDS 53,856 B.
// Overlays (barrier-separated):
//   st [198][136] shorts                  0 .. 53,856 B   (conv input stage)
//   oyL f32[64][73] 0..18,688 | oxL 18,688..37,376 | mskL f16[64][74] 37,376..46,848
//   Rbuf 4 x 64 x 36 f (stride 36 = conflict-free)  0..36,864 | A3 36,864..46,080
__global__ __launch_bounds__(512, 4) void k_omdcn(
        const unsigned short* __restrict__ offT, const uint4* __restrict__ fsC4,
        const unsigned short* __restrict__ Wb2, const float* __restrict__ bom,
        const unsigned short* __restrict__ wbd, const float* __restrict__ bd,
        const unsigned short* __restrict__ wbc,
        const float* __restrict__ s_cat, const float* __restrict__ b_cat,
        const float* __restrict__ feat_arm, float* __restrict__ feat) {
    __shared__ float LDSf[13464];                          // 53,856 B
    unsigned short* st = (unsigned short*)LDSf;
    float* oyL = LDSf;                                     // [64][73]
    float* oxL = LDSf + 4672;                              // [64][73]
    unsigned short* mskL = (unsigned short*)(LDSf + 9344); // [64][74] f16
    float* Rbuf = LDSf;                                    // 4 x 64 x 36 f
    unsigned short* A3 = (unsigned short*)(LDSf + 9216);   // [64][72] bf16 @36,864
    const uint4* offT4 = (const uint4*)offT;
    const uint4* W4 = (const uint4*)Wb2;
    const uint4* wbd4 = (const uint4*)wbd;
    const int t = threadIdx.x;
    const int b = blockIdx.x >> 6;
    const int h = blockIdx.x & 63;
    // ---- stage conv input rows h-1..h+1, 66 px, zero pad
    for (int i = t; i < 3 * 66 * 16; i += 512) {
        int q = i & 15;
        int rp = i >> 4;
        int r = rp / 66, p = rp - r * 66;
        int gy = h + r - 1, gx = p - 1;
        uint4 v = make_uint4(0, 0, 0, 0);
        if (gy >= 0 && gy < 64 && gx >= 0 && gx < 64)
            v = offT4[((((b << 6) + gy) << 6) + gx) * 16 + q];
        ((uint4*)(st + rp * 136))[q] = v;
    }
    __syncthreads();
    const int lane = t & 63;
    const int w = __builtin_amdgcn_readfirstlane(t >> 6);
    const int m = lane & 15, ko = lane >> 4;
    // ---- phase 1: conv3x3, N-split over 14 tiles: waves 0..6 own {2w,2w+1}
    f32x4 acc[2][4];   // [nt2][mt]
#pragma unroll
    for (int i = 0; i < 2; i++)
#pragma unroll
        for (int j = 0; j < 4; j++) acc[i][j] = (f32x4){0.f, 0.f, 0.f, 0.f};
    if (w < 7) {
        const int ntb = w << 1;
        uint4 b4c[2];
#pragma unroll
        for (int nt2 = 0; nt2 < 2; nt2++)
            b4c[nt2] = W4[((ntb + nt2) << 6) + lane];
#pragma unroll
        for (int kk = 0; kk < 36; kk++) {
            const int tap = kk >> 2, cc = kk & 3;
            const int dy = tap / 3, dx = tap - dy * 3;
            uint4 b4n[2];
            if (kk < 35) {
#pragma unroll
                for (int nt2 = 0; nt2 < 2; nt2++)
                    b4n[nt2] = W4[(((kk + 1) * 14 + ntb + nt2) << 6) + lane];
            }
            short8 a8[4];
#pragma unroll
            for (int mt = 0; mt < 4; mt++) {
                int p = mt * 16 + m + dx;
                a8[mt] = *(const short8*)(st + (dy * 66 + p) * 136 + (cc << 5) + (ko << 3));
            }
            __builtin_amdgcn_s_setprio(1);
#pragma unroll
            for (int nt2 = 0; nt2 < 2; nt2++)
#pragma unroll
                for (int mt = 0; mt < 4; mt++)
                    acc[nt2][mt] = __builtin_amdgcn_mfma_f32_16x16x32_bf16(
                        a8[mt], *(short8*)&b4c[nt2], acc[nt2][mt], 0, 0, 0);
            __builtin_amdgcn_s_setprio(0);
            if (kk < 35) {
#pragma unroll
                for (int nt2 = 0; nt2 < 2; nt2++) b4c[nt2] = b4n[nt2];
            }
        }
    }
    __syncthreads();                       // stage reads done -> om overlay safe
    // ---- phase 2: om -> split LDS; sigmoid applied to mask channels (f16)
    if (w < 7) {
#pragma unroll
        for (int nt2 = 0; nt2 < 2; nt2++) {
            int o = (((w << 1) + nt2) << 4) + m;
            if (o < 216) {
                float bv = bom[o];
#pragma unroll
                for (int mt = 0; mt < 4; mt++) {
                    f32x4 v = acc[nt2][mt];
#pragma unroll
                    for (int r = 0; r < 4; r++) {
                        int px = mt * 16 + (ko << 2) + r;
                        float val = v[r] + bv;
                        if (o < 72) {
                            oyL[px * 73 + o] = val;
                        } else if (o < 144) {
                            oxL[px * 73 + (o - 72)] = val;
                        } else {
                            float sg = 1.0f / (1.0f + __expf(-val));
                            mskL[px * 74 + (o - 144)] = f2h(sg);
                        }
                    }
                }
            }
        }
    }
    __syncthreads();
    // ---- phase 3: DCN sampling, 32x32x16 f16; wave = (px-half p2, K-quarter kq)
    // step s = kq*18+si: tap = si%9 (compile-time), g = 2kq+(si>=9), ch = s.
    const int p2 = w & 1;
    const int kq = w >> 1;
    const int oct = lane >> 5;
    const int l31 = lane & 31;
    const int px = (p2 << 5) + l31;
    const float fh = (float)h, fw = (float)px;
    const int b14 = b << 14;
    const float* oyrow = oyL + px * 73 + kq * 18;
    const float* oxrow = oxL + px * 73 + kq * 18;
    const unsigned short* mrow = mskL + px * 74 + kq * 18;
    const uint4* bp0 = fsC4 + b14 + (((kq << 2) + oct) << 10);
    const uint4* wbbase = wbd4 + (kq * 36) * 64 + lane;
    F16u acc3[2];
#pragma unroll
    for (int nt = 0; nt < 2; nt++)
#pragma unroll
        for (int q = 0; q < 4; q++) acc3[nt].q[q] = (f32x4){0.f, 0.f, 0.f, 0.f};
#pragma unroll
    for (int si = 0; si < 18; si++) {
        const int tap = si % 9;
        const int dy = tap / 3, dx = tap - dy * 3;
        float oy = oyrow[si];
        float ox = oxrow[si];
        float mmv = (float)(*(const _Float16*)(mrow + si));  // pre-sigmoided
        float py = fh + (float)(dy - 1) + oy;
        float pxx = fw + (float)(dx - 1) + ox;
        float y0f = floorf(py), x0f = floorf(pxx);
        float tyf = py - y0f, txf = pxx - x0f;
        int y0i = (int)y0f, x0i = (int)x0f;
        int y1i = y0i + 1, x1i = x0i + 1;
        bool vy0 = (y0i >= 0) && (y0i < 64);
        bool vy1 = (y1i >= 0) && (y1i < 64);
        bool vx0 = (x0i >= 0) && (x0i < 64);
        bool vx1 = (x1i >= 0) && (x1i < 64);
        float w00 = (vy0 && vx0) ? (1.0f - tyf) * (1.0f - txf) * mmv : 0.0f;
        float w01 = (vy0 && vx1) ? (1.0f - tyf) * txf * mmv : 0.0f;
        float w10 = (vy1 && vx0) ? tyf * (1.0f - txf) * mmv : 0.0f;
        float w11 = (vy1 && vx1) ? tyf * txf * mmv : 0.0f;
        int yc0 = y0i < 0 ? 0 : (y0i > 63 ? 63 : y0i);
        int yc1 = y1i < 0 ? 0 : (y1i > 63 ? 63 : y1i);
        int xc0 = x0i < 0 ? 0 : (x0i > 63 ? 63 : x0i);
        int xc1 = x1i < 0 ? 0 : (x1i > 63 ? 63 : x1i);
        int row0 = (yc0 >> 1) << 5, row1 = (yc1 >> 1) << 5;
        const uint4* bpp = (si < 9) ? bp0 : (bp0 + 2048);  // g += 1 -> ci += 2 planes
        uint4 c00 = bpp[row0 + (xc0 >> 1)];
        uint4 c01 = bpp[row0 + (xc1 >> 1)];
        uint4 c10 = bpp[row1 + (xc0 >> 1)];
        uint4 c11 = bpp[row1 + (xc1 >> 1)];
        _Float16 h00 = (_Float16)w00, h01 = (_Float16)w01;
        _Float16 h10 = (_Float16)w10, h11 = (_Float16)w11;
        h2 W00 = (h2){h00, h00}, W01 = (h2){h01, h01};
        h2 W10 = (h2){h10, h10}, W11 = (h2){h11, h11};
        union { uint4 u; h2 h[4]; } U00, U01, U10, U11;
        U00.u = c00; U01.u = c01; U10.u = c10; U11.u = c11;
        union { short8 s; h2 h[4]; } av;
#pragma unroll
        for (int c = 0; c < 4; c++)
            av.h[c] = U00.h[c] * W00 + U01.h[c] * W01 + U10.h[c] * W10 + U11.h[c] * W11;
        uint4 bu0 = wbbase[(si * 2) * 64];
        uint4 bu1 = wbbase[(si * 2 + 1) * 64];
        __builtin_amdgcn_s_setprio(1);
        acc3[0].v = __builtin_amdgcn_mfma_f32_32x32x16_f16(av.s, *(short8*)&bu0, acc3[0].v, 0, 0, 0);
        acc3[1].v = __builtin_amdgcn_mfma_f32_32x32x16_f16(av.s, *(short8*)&bu1, acc3[1].v, 0, 0, 0);
        __builtin_amdgcn_s_setprio(0);
    }
    __syncthreads();                       // om reads done -> Rbuf overlay safe
    // ---- 4-quarter reduction, two rounds through Rbuf (stride 36 f, conflict-free)
    if (kq >= 2) {
        float* rb = Rbuf + ((((kq - 2) << 1) + p2) * 64 + lane) * 36;
#pragma unroll
        for (int nt = 0; nt < 2; nt++)
#pragma unroll
            for (int q = 0; q < 4; q++)
                *(f32x4*)(rb + (nt << 4) + (q << 2)) = acc3[nt].q[q];
    }
    __syncthreads();
    if (kq < 2) {
        const float* rb = Rbuf + (((kq << 1) + p2) * 64 + lane) * 36;
#pragma unroll
        for (int nt = 0; nt < 2; nt++)
#pragma unroll
            for (int q = 0; q < 4; q++)
                acc3[nt].q[q] += *(const f32x4*)(rb + (nt << 4) + (q << 2));
    }
    __syncthreads();
    if (kq == 1) {
        float* rb = Rbuf + (p2 * 64 + lane) * 36;
#pragma unroll
        for (int nt = 0; nt < 2; nt++)
#pragma unroll
            for (int q = 0; q < 4; q++)
                *(f32x4*)(rb + (nt << 4) + (q << 2)) = acc3[nt].q[q];
    }
    __syncthreads();
    if (kq == 0) {
        const float* rb = Rbuf + (p2 * 64 + lane) * 36;
#pragma unroll
        for (int nt = 0; nt < 2; nt++)
#pragma unroll
            for (int q = 0; q < 4; q++)
                acc3[nt].q[q] += *(const f32x4*)(rb + (nt << 4) + (q << 2));
        // ---- phase 4a: align -> A3 bf16 [px][72]; 32x32 C/D mapping
#pragma unroll
        for (int nt = 0; nt < 2; nt++) {
            int o = (nt << 5) + l31;
            float bv = bd[o];
#pragma unroll
            for (int r = 0; r < 16; r++) {
                int rowm = (r & 3) + ((r >> 2) << 3) + (oct << 2);
                float v = acc3[nt].v[r] + bv;
                v = v > 0.f ? v : 0.f;
                A3[((p2 << 5) + rowm) * 72 + o] = f2bf(v);
            }
        }
    }
    __syncthreads();                       // A3 visible to all waves
    // ---- phase 4b: cat GEMM K=64, N=128 (16x16); wave = (px quarter nq, N-half kh)
    const int nq = w & 3;
    const int kh = w >> 2;
    f32x4 acc2[4];
#pragma unroll
    for (int nt2 = 0; nt2 < 4; nt2++) acc2[nt2] = (f32x4){0.f, 0.f, 0.f, 0.f};
#pragma unroll
    for (int kk2 = 0; kk2 < 2; kk2++) {
        short8 av = *(const short8*)(A3 + ((nq << 4) + m) * 72 + kk2 * 32 + (ko << 3));
#pragma unroll
        for (int nt2 = 0; nt2 < 4; nt2++) {
            uint4 bu = ((const uint4*)wbc)[(kk2 * 8 + (kh << 2) + nt2) * 64 + lane];
            acc2[nt2] = __builtin_amdgcn_mfma_f32_16x16x32_bf16(av, *(short8*)&bu, acc2[nt2], 0, 0, 0);
        }
    }
    // ---- phase 4c: direct float4 epilogue (feat_arm preload + fused store)
    {
        const int px0 = (nq << 4) + (ko << 2);
        const int base = (b << 19) + (h << 6) + px0;
        f32x4 fa[4];
#pragma unroll
        for (int nt2 = 0; nt2 < 4; nt2++) {
            int o = (((kh << 2) + nt2) << 4) + m;
            fa[nt2] = *(const f32x4*)(feat_arm + base + (o << 12));
        }
#pragma unroll
        for (int nt2 = 0; nt2 < 4; nt2++) {
            int o = (((kh << 2) + nt2) << 4) + m;
            float sc = s_cat[o], bi = b_cat[o];
            f32x4 v;
#pragma unroll
            for (int r = 0; r < 4; r++) {
                float vv = fmaf(acc2[nt2][r], sc, bi);
                vv = vv > 0.f ? vv : 0.f;
                v[r] = vv + fa[nt2][r];
            }
            *(f32x4*)(feat + base + (o << 12)) = v;
        }
    }
}

extern "C" void kernel_launch(void* const* d_in, const int* in_sizes, int n_in,
                              void* d_out, int out_size, void* d_ws, size_t ws_size,
                              hipStream_t stream) {
    const float* feat_l = (const float*)d_in[0];
    const float* feat_s = (const float*)d_in[1];
    const float* W_fsm  = (const float*)d_in[2];
    const float* s_fsm  = (const float*)d_in[3];
    const float* b_fsm  = (const float*)d_in[4];
    const float* W_off  = (const float*)d_in[5];
    const float* s_off  = (const float*)d_in[6];
    const float* b_off  = (const float*)d_in[7];
    const float* W_om   = (const float*)d_in[8];
    const float* b_om   = (const float*)d_in[9];
    const float* W_dcn  = (const float*)d_in[10];
    const float* b_dcn  = (const float*)d_in[11];
    const float* W_cat  = (const float*)d_in[12];
    const float* s_cat  = (const float*)d_in[13];
    const float* b_cat  = (const float*)d_in[14];

    float* feat     = (float*)d_out;
    float* feat_arm = feat + 4194304;

    float* ws = (float*)d_ws;
    unsigned short* offT = (unsigned short*)ws;                // 2,097,152 f
    uint4* fsT4  = (uint4*)(ws + 9175040);                     //   524,288 f
    unsigned short* wb2   = (unsigned short*)(ws + 9699328);   //  147,456 f
    unsigned short* wbfsm = (unsigned short*)(ws + 9846784);   //    8,192 f
    unsigned short* wboff = (unsigned short*)(ws + 9854976);   //   16,384 f
    unsigned short* wbcat = (unsigned short*)(ws + 9871360);   //    4,096 f
    unsigned short* wbdcn = (unsigned short*)(ws + 9875456);   //   36,864 f
    uint4* fsC4  = (uint4*)(ws + 9912320);                     //   524,288 f

    k_prep<<<318, 256, 0, stream>>>(feat_s, fsT4, fsC4, W_fsm, W_off, W_cat,
                                    W_dcn, W_om, wbfsm, wboff, wbcat, wbdcn, wb2);

    k12<<<512, 512, 0, stream>>>(feat_l, fsT4, wbfsm, wboff,
                                 s_fsm, b_fsm, s_off, b_off, feat_arm, offT);
    k_omdcn<<<512, 512, 0, stream>>>(offT, fsC4, wb2, b_om, wbdcn, b_dcn,
                                     wbcat, s_cat, b_cat, feat_arm, feat);
}